// Round 1
// baseline (546.990 us; speedup 1.0000x reference)
//
#include <hip/hip_runtime.h>

static constexpr int N = 192;   // spatial extent, all 3 dims
static constexpr int K = 10;    // FIR truncation radius: |z|^(K+1) ~ 5e-7

// Combined causal+anticausal cubic-spline prefilter == convolution of the
// half-sample-mirrored periodic extension with  h[k] = sqrt(3) * z^{|k|},
// z = sqrt(3)-2.  (gain 6 folded in: -6z/(1-z^2) = sqrt(3).)
struct WTab { float w[K + 1]; };
static constexpr WTab make_wtab() {
    WTab t{};
    double z = -0.26794919243112270647;   // sqrt(3) - 2
    double A = 1.73205080756887729353;    // sqrt(3)
    double p = 1.0;
    for (int k = 0; k <= K; ++k) { t.w[k] = (float)(A * p); p *= z; }
    return t;
}
static constexpr WTab HW = make_wtab();

// half-sample mirror (DCT-II): valid for i in [-N, 2N-1]
__device__ __forceinline__ int mir(int i) {
    i = (i < 0) ? (-1 - i) : i;
    return (i >= N) ? (2 * N - 1 - i) : i;
}

// ---- Pass along innermost axis (stride 1) --------------------------------
// 256 threads stage 16 contiguous rows (16*192 f32 = 12 KB + pad) in LDS.
// Each thread computes a run of 12 outputs from a 32-float register window.
__global__ __launch_bounds__(256)
void kpass_x(const float* __restrict__ in, float* __restrict__ out) {
    __shared__ float s[16][N + 1];      // +1 pad: conflict-free strided reads
    const int t = threadIdx.x;
    const int base = blockIdx.x * (16 * N);
    const float4* g4 = (const float4*)(in + base);
    #pragma unroll
    for (int i = 0; i < 3; ++i) {       // 768 float4 / 256 threads
        const int q = t + i * 256;
        const float4 v = g4[q];
        const int e = q * 4;
        const int r = e / N;
        const int c = e - r * N;        // 192 % 4 == 0: never crosses a row
        s[r][c] = v.x; s[r][c + 1] = v.y; s[r][c + 2] = v.z; s[r][c + 3] = v.w;
    }
    __syncthreads();
    const int r  = t >> 4;
    const int xb = (t & 15) * 12;
    float win[12 + 2 * K];
    #pragma unroll
    for (int j = 0; j < 12 + 2 * K; ++j) win[j] = s[r][mir(xb + j - K)];
    float o[12];
    #pragma unroll
    for (int m = 0; m < 12; ++m) {
        float acc = HW.w[0] * win[m + K];
        #pragma unroll
        for (int k = 1; k <= K; ++k)
            acc += HW.w[k] * (win[m + K - k] + win[m + K + k]);
        o[m] = acc;
    }
    float4* o4 = (float4*)(out + base + r * N + xb);   // xb*4B is 16B-aligned
    #pragma unroll
    for (int i = 0; i < 3; ++i)
        o4[i] = make_float4(o[4 * i], o[4 * i + 1], o[4 * i + 2], o[4 * i + 3]);
}

// ---- Pass along a strided axis (y: AS=192, z: AS=192*192) ----------------
// Block stages a full-axis 192 x 64 slab (48 KB LDS, 3 blocks/CU); lanes run
// along the stride-1 x dim so every global access is a 256 B coalesced line.
// slab_base = (by/odiv)*os_hi + (by%odiv)*os_lo + blockIdx.x*64
__global__ __launch_bounds__(256)
void kpass_s(const float* __restrict__ in, float* __restrict__ out,
             const int AS, const int odiv, const int os_hi, const int os_lo) {
    __shared__ float s[N][64];          // [axis][lane]: reads are 2-way (free)
    const int t = threadIdx.x;
    const int by = blockIdx.y;
    const int slab = (by / odiv) * os_hi + (by % odiv) * os_lo + blockIdx.x * 64;
    #pragma unroll
    for (int i = 0; i < 12; ++i) {      // 3072 float4 / 256 threads
        const int q = t + i * 256;
        const int j = q >> 4;           // axis index 0..191
        const int m4 = (q & 15) * 4;
        const float4 v = *(const float4*)(in + slab + j * AS + m4);
        s[j][m4] = v.x; s[j][m4 + 1] = v.y; s[j][m4 + 2] = v.z; s[j][m4 + 3] = v.w;
    }
    __syncthreads();
    const int m = t & 63;
    const int g = t >> 6;
    #pragma unroll
    for (int rr = 0; rr < 3; ++rr) {    // 12 runs of 16 / 4 groups
        const int jb = (g + rr * 4) * 16;
        float win[16 + 2 * K];
        #pragma unroll
        for (int j = 0; j < 16 + 2 * K; ++j) win[j] = s[mir(jb + j - K)][m];
        #pragma unroll
        for (int mm = 0; mm < 16; ++mm) {
            float acc = HW.w[0] * win[mm + K];
            #pragma unroll
            for (int k = 1; k <= K; ++k)
                acc += HW.w[k] * (win[mm + K - k] + win[mm + K + k]);
            out[slab + (jb + mm) * AS + m] = acc;
        }
    }
}

extern "C" void kernel_launch(void* const* d_in, const int* in_sizes, int n_in,
                              void* d_out, int out_size, void* d_ws, size_t ws_size,
                              hipStream_t stream) {
    const float* x = (const float*)d_in[0];
    float* out = (float*)d_out;
    float* ws  = (float*)d_ws;          // needs 226.5 MB scratch

    const int ROWS = 4 * 2 * N * N;     // 294912 x-rows
    // pass 1: filter x (innermost), in -> out
    kpass_x<<<ROWS / 16, 256, 0, stream>>>(x, out);
    // pass 2: filter y (stride 192), out -> ws ; slab per (b*c*z) plane
    kpass_s<<<dim3(3, 4 * 2 * N), 256, 0, stream>>>(out, ws, N, 1, N * N, 0);
    // pass 3: filter z (stride 192*192), ws -> out ; slab per (b*c, y)
    kpass_s<<<dim3(3, 4 * 2 * N), 256, 0, stream>>>(ws, out, N * N, N, N * N * N, N);
}